// Round 1
// baseline (700.910 us; speedup 1.0000x reference)
//
#include <hip/hip_runtime.h>
#include <hip/hip_bf16.h>

#define D 64

// ---------------------------------------------------------------------------
// K1: out-degree histogram over source nodes (float counts, exact for small deg)
__global__ __launch_bounds__(256) void deg_kernel(const int* __restrict__ n1,
                                                  float* __restrict__ deg, int E) {
    int e = blockIdx.x * 256 + threadIdx.x;
    if (e < E) atomicAdd(&deg[n1[e]], 1.0f);
}

// K2: deg -> rsqrt(deg) in place (deg >= 1 guaranteed: every node is a source)
__global__ __launch_bounds__(256) void rsqrt_kernel(float* __restrict__ deg, int N) {
    int i = blockIdx.x * 256 + threadIdx.x;
    if (i < N) deg[i] = rsqrtf(deg[i]);
}

// K3: h = X @ W^T + b.  One wave per row; lane d owns output dim d.
// W staged transposed in LDS: Wt[k][d] = W[d*64+k]; lanes read consecutive d
// (2 lanes/bank -> free).  x broadcast across the wave via __shfl.
__global__ __launch_bounds__(256) void linear_kernel(const float* __restrict__ x,
                                                     const float* __restrict__ W,
                                                     const float* __restrict__ b,
                                                     float* __restrict__ h, int N) {
    __shared__ float Wt[D][D];
    __shared__ float bs[D];
    int tid = threadIdx.x;
    for (int i = tid; i < D * D; i += 256) {
        int d = i >> 6, k = i & 63;
        Wt[k][d] = W[i];
    }
    if (tid < D) bs[tid] = b[tid];
    __syncthreads();

    int lane = tid & 63;
    int wave = tid >> 6;
    for (int row = blockIdx.x * 4 + wave; row < N; row += gridDim.x * 4) {
        float xl  = x[row * D + lane];   // lane holds x[row][lane]
        float acc = bs[lane];
        #pragma unroll
        for (int k = 0; k < D; ++k) {
            float xv = __shfl(xl, k, 64);
            acc += xv * Wt[k][lane];
        }
        h[row * D + lane] = acc;
    }
}

// K4: per-edge scatter.  One wave per edge; lane d does
//     out[n1*64+d] += w * h[n2*64+d]   (atomic, unsorted n1)
__global__ __launch_bounds__(256) void scatter_kernel(const int* __restrict__ ei,
                                                      const float* __restrict__ dist,
                                                      const float* __restrict__ rd,
                                                      const float* __restrict__ h,
                                                      float* __restrict__ out, int E) {
    int wid  = blockIdx.x * 4 + (threadIdx.x >> 6);
    int lane = threadIdx.x & 63;
    if (wid >= E) return;
    int   n1 = ei[wid];
    int   n2 = ei[E + wid];
    float dv = dist[wid];
    float w  = rd[n1] * rd[n2] * __expf(-dv * dv);
    atomicAdd(&out[n1 * D + lane], w * h[n2 * D + lane]);
}

// K5: leaky_relu + row L2-normalize.  One wave per node; 6-step shfl_xor reduce.
__global__ __launch_bounds__(256) void finalize_kernel(float* __restrict__ out, int N) {
    int wid  = blockIdx.x * 4 + (threadIdx.x >> 6);
    int lane = threadIdx.x & 63;
    if (wid >= N) return;
    float v = out[wid * D + lane];
    v = v > 0.0f ? v : 0.01f * v;
    float ss = v * v;
    #pragma unroll
    for (int m = 32; m; m >>= 1) ss += __shfl_xor(ss, m, 64);
    float norm = sqrtf(ss);
    out[wid * D + lane] = v / fmaxf(norm, 1e-12f);
}

extern "C" void kernel_launch(void* const* d_in, const int* in_sizes, int n_in,
                              void* d_out, int out_size, void* d_ws, size_t ws_size,
                              hipStream_t stream) {
    const float* poi  = (const float*)d_in[0];
    const int*   ei   = (const int*)d_in[1];
    const float* dist = (const float*)d_in[2];
    const float* W    = (const float*)d_in[3];
    const float* b    = (const float*)d_in[4];
    float*       out  = (float*)d_out;

    int N = in_sizes[0] / D;   // 100000
    int E = in_sizes[2];       // 1280000

    // workspace layout: [0, N*4)        : deg -> rsqrt(deg)
    //                   [1MB, 1MB+N*D*4): h = X W^T + b
    float* rd = (float*)d_ws;
    float* h  = (float*)((char*)d_ws + (1u << 20));

    // zero accumulators (harness poisons d_out/d_ws with 0xAA every call)
    hipMemsetAsync(rd, 0, (size_t)N * sizeof(float), stream);
    hipMemsetAsync(out, 0, (size_t)N * D * sizeof(float), stream);

    deg_kernel<<<(E + 255) / 256, 256, 0, stream>>>(ei, rd, E);
    rsqrt_kernel<<<(N + 255) / 256, 256, 0, stream>>>(rd, N);
    linear_kernel<<<(N + 3) / 4, 256, 0, stream>>>(poi, W, b, h, N);
    scatter_kernel<<<(E + 3) / 4, 256, 0, stream>>>(ei, dist, rd, h, out, E);
    finalize_kernel<<<(N + 3) / 4, 256, 0, stream>>>(out, N);
}